// Round 6
// baseline (2332.306 us; speedup 1.0000x reference)
//
#include <hip/hip_runtime.h>
#include <math.h>

#define NND 50000
#define NED 800000
#define HD  128
#define NG  64
#define MT  32

typedef __attribute__((ext_vector_type(8))) short short8v;
typedef __attribute__((ext_vector_type(4))) float float4v;
typedef __attribute__((ext_vector_type(2))) float float2v;

__device__ __forceinline__ float gelu_t(float x) {
  const float c = 0.7978845608028654f;
  float t = tanhf(c * (x + 0.044715f * x * x * x));
  return 0.5f * x * (1.0f + t);
}

__device__ __forceinline__ unsigned short f2bf(float f) {
  unsigned int u = __float_as_uint(f);
  u += 0x7FFFu + ((u >> 16) & 1u);
  return (unsigned short)(u >> 16);
}
__device__ __forceinline__ float bf2f(unsigned short s) {
  return __uint_as_float(((unsigned int)s) << 16);
}
__device__ __forceinline__ float bflo(unsigned int u) { return __uint_as_float(u << 16); }
__device__ __forceinline__ float bfhi(unsigned int u) { return __uint_as_float(u & 0xFFFF0000u); }
__device__ __forceinline__ unsigned char f2fp8(float f) {
  return (unsigned char)(__builtin_amdgcn_cvt_pk_fp8_f32(f, f, 0, false) & 0xFF);
}

// ---------------- CSR build ----------------
__global__ void k_hist(const int* __restrict__ dst, int* __restrict__ degi) {
  int e = blockIdx.x * 256 + threadIdx.x;
  if (e < NED) atomicAdd(&degi[dst[e]], 1);
}

__global__ __launch_bounds__(1024) void k_scan(
    const int* __restrict__ degi, int* __restrict__ rowptr,
    int* __restrict__ cursor, float* __restrict__ deginv) {
  __shared__ int wsum[16];
  int tid = threadIdx.x;
  int lane = tid & 63;
  int wid = tid >> 6;
  int running = 0;
  for (int base = 0; base < NND; base += 1024) {
    int idx = base + tid;
    int v = (idx < NND) ? degi[idx] : 0;
    int s = v;
#pragma unroll
    for (int o = 1; o < 64; o <<= 1) {
      int t = __shfl_up(s, o, 64);
      if (lane >= o) s += t;
    }
    if (lane == 63) wsum[wid] = s;
    __syncthreads();
    if (wid == 0) {
      int ws = (lane < 16) ? wsum[lane] : 0;
#pragma unroll
      for (int o = 1; o < 16; o <<= 1) {
        int t = __shfl_up(ws, o, 64);
        if (lane >= o) ws += t;
      }
      if (lane < 16) wsum[lane] = ws;
    }
    __syncthreads();
    int woff = wid ? wsum[wid - 1] : 0;
    int excl = running + woff + s - v;
    if (idx < NND) {
      rowptr[idx] = excl;
      cursor[idx] = excl;
      deginv[idx] = 1.0f / (float)max(v, 1);
    }
    int tot = wsum[15];
    __syncthreads();
    running += tot;
  }
  if (tid == 0) rowptr[NND] = running;
}

__global__ void k_scatter(const int* __restrict__ src, const int* __restrict__ dst,
                          int* __restrict__ cursor, int* __restrict__ csrsrc) {
  int e = blockIdx.x * 256 + threadIdx.x;
  if (e < NED) {
    int d = dst[e];
    int pos = atomicAdd(&cursor[d], 1);
    csrsrc[pos] = src[e];
  }
}

__global__ void k_cnt(const int* __restrict__ batch, float* __restrict__ cnt) {
  int g = threadIdx.x;
  if (g >= NG) return;
  int lo, hi, ub_g, ub_gm1;
  lo = 0; hi = NND;
  while (lo < hi) { int mid = (lo + hi) >> 1; if (batch[mid] <= g) lo = mid + 1; else hi = mid; }
  ub_g = lo;
  if (g == 0) ub_gm1 = 0;
  else {
    lo = 0; hi = NND;
    int v = g - 1;
    while (lo < hi) { int mid = (lo + hi) >> 1; if (batch[mid] <= v) lo = mid + 1; else hi = mid; }
    ub_gm1 = lo;
  }
  cnt[g] = (float)(ub_g - ub_gm1);
}

__global__ void k_weff(const float* __restrict__ Wint, float* __restrict__ weff) {
  int i = blockIdx.x * 256 + threadIdx.x;
  if (i < HD * HD) weff[i] = Wint[i] + Wint[i + HD * HD];
}

__global__ void k_prepB(const float* __restrict__ Wself, const float* __restrict__ Wmsg,
                        unsigned short* __restrict__ Bt) {
  int i = blockIdx.x * 256 + threadIdx.x;
  if (i < 128 * 256) {
    int n = i >> 8, k = i & 255;
    float w = (k < HD) ? Wself[k * HD + n] : Wmsg[(k - HD) * HD + n];
    Bt[i] = f2bf(w);
  }
}

__global__ void k_prepIn(const float* __restrict__ Win, const float* __restrict__ Walt,
                         unsigned short* __restrict__ BtIn) {
  int i = blockIdx.x * 256 + threadIdx.x;
  if (i < 2 * 128 * 128) {
    int p = i >> 14; int rem = i & 16383; int n = rem >> 7; int k = rem & 127;
    const float* W = p ? Walt : Win;
    BtIn[i] = f2bf(W[k * 128 + n]);
  }
}

// ---------------- init (MFMA) ----------------
__global__ __launch_bounds__(256) void k_init2(
    const float* __restrict__ x, const unsigned short* __restrict__ BtIn,
    const float* __restrict__ bin, const float* __restrict__ gin, const float* __restrict__ bein,
    const float* __restrict__ balt, const float* __restrict__ galt, const float* __restrict__ bealt,
    const float* __restrict__ alphap, const float* __restrict__ betap,
    float* __restrict__ hdst, unsigned short* __restrict__ hbf)
{
  __shared__ float red[4][16][2];
  __shared__ unsigned short gtile[2][16][64];
  int tid = threadIdx.x;
  int wave = tid >> 6;
  int lane = tid & 63;
  int l15 = lane & 15;
  int lhi = lane >> 4;
  int path = wave >> 1;
  int colBase = (wave & 1) * 64;
  int rowBase = blockIdx.x * 64;

  const unsigned short* Bp = BtIn + path * 128 * 128;
  short8v bfr[4][4];
#pragma unroll
  for (int t = 0; t < 4; ++t) {
    int n = colBase + t * 16 + l15;
#pragma unroll
    for (int s = 0; s < 4; ++s)
      bfr[t][s] = *(const short8v*)&Bp[n * 128 + s * 32 + lhi * 8];
  }

  const float* bvp = path ? balt : bin;
  const float* gp  = path ? galt : gin;
  const float* bep = path ? bealt : bein;
  float bv[4], gw[4], bew[4];
#pragma unroll
  for (int t = 0; t < 4; ++t) {
    int col = colBase + t * 16 + l15;
    bv[t] = bvp[col]; gw[t] = gp[col]; bew[t] = bep[col];
  }

  float al = alphap[0], btv = betap[0];
  float nrm = sqrtf(al * al + btv * btv);
  float w0 = fabsf(al) / nrm, w1 = fabsf(btv) / nrm;

  for (int rt = 0; rt < 4; ++rt) {
    int arow = rowBase + rt * 16 + l15; if (arow >= NND) arow = NND - 1;
    short8v afr[4];
#pragma unroll
    for (int s = 0; s < 4; ++s) {
      float4 xa = *(const float4*)&x[(size_t)arow * HD + s * 32 + lhi * 8];
      float4 xb = *(const float4*)&x[(size_t)arow * HD + s * 32 + lhi * 8 + 4];
      short8v f;
      f[0] = (short)f2bf(xa.x); f[1] = (short)f2bf(xa.y);
      f[2] = (short)f2bf(xa.z); f[3] = (short)f2bf(xa.w);
      f[4] = (short)f2bf(xb.x); f[5] = (short)f2bf(xb.y);
      f[6] = (short)f2bf(xb.z); f[7] = (short)f2bf(xb.w);
      afr[s] = f;
    }

    float4v acc[4];
#pragma unroll
    for (int t = 0; t < 4; ++t) acc[t] = (float4v){0.f, 0.f, 0.f, 0.f};
#pragma unroll
    for (int s = 0; s < 4; ++s) {
#pragma unroll
      for (int t = 0; t < 4; ++t)
        acc[t] = __builtin_amdgcn_mfma_f32_16x16x32_bf16(afr[s], bfr[t][s], acc[t], 0, 0, 0);
    }

    float z[4][4];
    float psum[4], psq[4];
#pragma unroll
    for (int r = 0; r < 4; ++r) {
      float s1 = 0.f, s2 = 0.f;
#pragma unroll
      for (int t = 0; t < 4; ++t) {
        float zz = acc[t][r] + bv[t];
        z[r][t] = zz;
        s1 += zz; s2 += zz * zz;
      }
#pragma unroll
      for (int m = 1; m < 16; m <<= 1) {
        s1 += __shfl_xor(s1, m, 16);
        s2 += __shfl_xor(s2, m, 16);
      }
      psum[r] = s1; psq[r] = s2;
    }
    if (l15 == 0) {
#pragma unroll
      for (int r = 0; r < 4; ++r) {
        red[wave][lhi * 4 + r][0] = psum[r];
        red[wave][lhi * 4 + r][1] = psq[r];
      }
    }
    __syncthreads();

    int pw = wave ^ 1;
    float gval[4][4];
#pragma unroll
    for (int r = 0; r < 4; ++r) {
      int rowl = lhi * 4 + r;
      float S = psum[r] + red[pw][rowl][0];
      float Q = psq[r]  + red[pw][rowl][1];
      float mean = S * (1.0f / 128.0f);
      float var  = Q * (1.0f / 128.0f) - mean * mean;
      float rs = rsqrtf(var + 1e-5f);
#pragma unroll
      for (int t = 0; t < 4; ++t)
        gval[r][t] = gelu_t((z[r][t] - mean) * rs * gw[t] + bew[t]);
    }

    if (path == 1) {
#pragma unroll
      for (int r = 0; r < 4; ++r)
#pragma unroll
        for (int t = 0; t < 4; ++t)
          gtile[wave & 1][lhi * 4 + r][t * 16 + l15] = f2bf(gval[r][t]);
    }
    __syncthreads();

    if (path == 0) {
#pragma unroll
      for (int r = 0; r < 4; ++r) {
        int m = rowBase + rt * 16 + lhi * 4 + r;
        if (m < NND) {
#pragma unroll
          for (int t = 0; t < 4; ++t) {
            float g1 = bf2f(gtile[wave & 1][lhi * 4 + r][t * 16 + l15]);
            float hv = w0 * gval[r][t] + w1 * g1;
            size_t off = (size_t)m * HD + colBase + t * 16 + l15;
            hdst[off] = hv;
            hbf[off] = f2bf(hv);
          }
        }
      }
    }
    __syncthreads();
  }
}

// ---------------- fused stage: gather(u) + MFMA GEMM + RK4 epilogue ----------------
// stage0: u = meanagg(hbf) [bf16 gather]; save usav
// stage1-3: u = usav + cu*meanagg(k8)  [fp8 gather]
// epilogue: kv = tanh(.); st<3: ybf = bf(hbf + cy*kv), kacc += wk*kv (bf16), k8w = fp8(kv)
//           st3: h = h + kacc + wk*kv (fp32), hbf = bf(h)
__global__ __launch_bounds__(256) void k_fused(
    const unsigned short* __restrict__ ain,   // A rows: hbf (st0) or ybf
    const unsigned short* __restrict__ hbf,   // step-base h (bf16)
    const unsigned char* __restrict__ k8r,    // fp8 k gather source (st>0)
    unsigned char* __restrict__ k8w,          // fp8 k write (st<3)
    unsigned short* __restrict__ usav,        // bf16 u_h
    unsigned short* __restrict__ kacc,        // bf16 sum wk*k
    const int* __restrict__ rowptr, const int* __restrict__ csrsrc,
    const float* __restrict__ deginv,
    const unsigned short* __restrict__ Bt, const float* __restrict__ bode,
    float* __restrict__ hfp,                  // fp32 h (r/w at st3 only)
    unsigned short* __restrict__ ybf,
    unsigned short* __restrict__ hbfout, int stage)
{
  __shared__ unsigned char u_lds[MT * 256];   // MT rows x 128 bf16, XOR-swizzled
  int tid = threadIdx.x;
  int wave = tid >> 6;
  int lane = tid & 63;
  int l15 = lane & 15;
  int lhi = lane >> 4;
  int rowBase = blockIdx.x * MT;
  int ncol0 = wave * 32;

  const float DT = 0.125f;
  float wk = (stage == 0 || stage == 3) ? DT / 6.0f : DT / 3.0f;
  float cy = (stage <= 1) ? 0.5f * DT : DT;
  float cu = (stage == 3) ? DT : 0.5f * DT;

  if (stage == 0) {
    // ---- bf16 gather of h rows: 16-lane groups ----
    int l16 = tid & 15;
    int grp = tid >> 4;
#pragma unroll
    for (int g = 0; g < MT / 16; ++g) {
      int nloc = g * 16 + grp;
      int node = rowBase + nloc;
      if (node < NND) {
        int e0 = rowptr[node], e1 = rowptr[node + 1];
        float a0=0,a1=0,a2=0,a3=0,a4=0,a5=0,a6=0,a7=0;
        for (int eb = e0; eb < e1; eb += 8) {
          int n8 = e1 - eb; if (n8 > 8) n8 = 8;
          int sidx[8];
#pragma unroll
          for (int j = 0; j < 8; ++j) sidx[j] = csrsrc[eb + ((j < n8) ? j : 0)];
#pragma unroll
          for (int j = 0; j < 8; ++j) {
            if (j < n8) {
              uint4 v = *(const uint4*)&hbf[(size_t)sidx[j] * HD + l16 * 8];
              a0 += bflo(v.x); a1 += bfhi(v.x); a2 += bflo(v.y); a3 += bfhi(v.y);
              a4 += bflo(v.z); a5 += bfhi(v.z); a6 += bflo(v.w); a7 += bfhi(v.w);
            }
          }
        }
        float di = deginv[node];
        uint4 o;
        o.x = (unsigned int)f2bf(a0*di) | ((unsigned int)f2bf(a1*di) << 16);
        o.y = (unsigned int)f2bf(a2*di) | ((unsigned int)f2bf(a3*di) << 16);
        o.z = (unsigned int)f2bf(a4*di) | ((unsigned int)f2bf(a5*di) << 16);
        o.w = (unsigned int)f2bf(a6*di) | ((unsigned int)f2bf(a7*di) << 16);
        unsigned int boff = (unsigned int)nloc * 256u +
            (((unsigned int)l16 * 16u) ^ (((unsigned int)nloc & 7u) << 4));
        *(uint4*)&u_lds[boff] = o;
        *(uint4*)&usav[(size_t)node * HD + l16 * 8] = o;
      }
    }
  } else {
    // ---- fp8 gather of k rows: 8-lane groups (128B rows) ----
    int l8 = tid & 7;
    int grp = tid >> 3;   // 0..31
#pragma unroll
    for (int g = 0; g < MT / 32; ++g) {
      int nloc = g * 32 + grp;
      int node = rowBase + nloc;
      if (node < NND) {
        int e0 = rowptr[node], e1 = rowptr[node + 1];
        float a[16];
#pragma unroll
        for (int q = 0; q < 16; ++q) a[q] = 0.f;
        for (int eb = e0; eb < e1; eb += 8) {
          int n8 = e1 - eb; if (n8 > 8) n8 = 8;
          int sidx[8];
#pragma unroll
          for (int j = 0; j < 8; ++j) sidx[j] = csrsrc[eb + ((j < n8) ? j : 0)];
#pragma unroll
          for (int j = 0; j < 8; ++j) {
            if (j < n8) {
              uint4 v = *(const uint4*)&k8r[(size_t)sidx[j] * HD + l8 * 16];
              float2v f0 = __builtin_amdgcn_cvt_pk_f32_fp8(v.x, false);
              float2v f1 = __builtin_amdgcn_cvt_pk_f32_fp8(v.x, true);
              float2v f2 = __builtin_amdgcn_cvt_pk_f32_fp8(v.y, false);
              float2v f3 = __builtin_amdgcn_cvt_pk_f32_fp8(v.y, true);
              float2v f4 = __builtin_amdgcn_cvt_pk_f32_fp8(v.z, false);
              float2v f5 = __builtin_amdgcn_cvt_pk_f32_fp8(v.z, true);
              float2v f6 = __builtin_amdgcn_cvt_pk_f32_fp8(v.w, false);
              float2v f7 = __builtin_amdgcn_cvt_pk_f32_fp8(v.w, true);
              a[0]+=f0[0]; a[1]+=f0[1]; a[2]+=f1[0]; a[3]+=f1[1];
              a[4]+=f2[0]; a[5]+=f2[1]; a[6]+=f3[0]; a[7]+=f3[1];
              a[8]+=f4[0]; a[9]+=f4[1]; a[10]+=f5[0]; a[11]+=f5[1];
              a[12]+=f6[0]; a[13]+=f6[1]; a[14]+=f7[0]; a[15]+=f7[1];
            }
          }
        }
        float di = deginv[node] * cu;
        uint4 us0 = *(const uint4*)&usav[(size_t)node * HD + l8 * 16];
        uint4 us1 = *(const uint4*)&usav[(size_t)node * HD + l8 * 16 + 8];
        float u0  = bflo(us0.x) + a[0]*di,  u1  = bfhi(us0.x) + a[1]*di;
        float u2  = bflo(us0.y) + a[2]*di,  u3  = bfhi(us0.y) + a[3]*di;
        float u4  = bflo(us0.z) + a[4]*di,  u5  = bfhi(us0.z) + a[5]*di;
        float u6  = bflo(us0.w) + a[6]*di,  u7  = bfhi(us0.w) + a[7]*di;
        float u8  = bflo(us1.x) + a[8]*di,  u9  = bfhi(us1.x) + a[9]*di;
        float u10 = bflo(us1.y) + a[10]*di, u11 = bfhi(us1.y) + a[11]*di;
        float u12 = bflo(us1.z) + a[12]*di, u13 = bfhi(us1.z) + a[13]*di;
        float u14 = bflo(us1.w) + a[14]*di, u15 = bfhi(us1.w) + a[15]*di;
        uint4 o0, o1;
        o0.x = (unsigned int)f2bf(u0)  | ((unsigned int)f2bf(u1)  << 16);
        o0.y = (unsigned int)f2bf(u2)  | ((unsigned int)f2bf(u3)  << 16);
        o0.z = (unsigned int)f2bf(u4)  | ((unsigned int)f2bf(u5)  << 16);
        o0.w = (unsigned int)f2bf(u6)  | ((unsigned int)f2bf(u7)  << 16);
        o1.x = (unsigned int)f2bf(u8)  | ((unsigned int)f2bf(u9)  << 16);
        o1.y = (unsigned int)f2bf(u10) | ((unsigned int)f2bf(u11) << 16);
        o1.z = (unsigned int)f2bf(u12) | ((unsigned int)f2bf(u13) << 16);
        o1.w = (unsigned int)f2bf(u14) | ((unsigned int)f2bf(u15) << 16);
        unsigned int base = (unsigned int)nloc * 256u;
        unsigned int sw = ((unsigned int)nloc & 7u) << 4;
        *(uint4*)&u_lds[base + (((unsigned int)l8 * 32u) ^ sw)] = o0;
        *(uint4*)&u_lds[base + (((unsigned int)l8 * 32u + 16u) ^ sw)] = o1;
      }
    }
  }

  // ---- B fragments ----
  short8v bfr[2][8];
#pragma unroll
  for (int t = 0; t < 2; ++t) {
    int n = ncol0 + t * 16 + l15;
#pragma unroll
    for (int s = 0; s < 8; ++s) {
      bfr[t][s] = *(const short8v*)&Bt[n * 256 + s * 32 + lhi * 8];
    }
  }
  float bo0 = bode[ncol0 + l15];
  float bo1 = bode[ncol0 + 16 + l15];

  __syncthreads();

  // ---- MFMA + epilogue ----
#pragma unroll
  for (int rt = 0; rt < MT / 16; ++rt) {
    int rloc = rt * 16 + l15;
    int mload = rowBase + rloc;
    if (mload >= NND) mload = NND - 1;
    short8v afr[8];
#pragma unroll
    for (int s = 0; s < 4; ++s)
      afr[s] = *(const short8v*)&ain[(size_t)mload * HD + s * 32 + lhi * 8];
#pragma unroll
    for (int s = 0; s < 4; ++s) {
      unsigned int boff = (unsigned int)rloc * 256u +
        ((((unsigned int)s * 64u) + ((unsigned int)lhi * 16u)) ^ (((unsigned int)rloc & 7u) << 4));
      afr[4 + s] = *(const short8v*)&u_lds[boff];
    }

    float4v acc0 = {0.f, 0.f, 0.f, 0.f};
    float4v acc1 = {0.f, 0.f, 0.f, 0.f};
#pragma unroll
    for (int s = 0; s < 8; ++s) {
      acc0 = __builtin_amdgcn_mfma_f32_16x16x32_bf16(afr[s], bfr[0][s], acc0, 0, 0, 0);
      acc1 = __builtin_amdgcn_mfma_f32_16x16x32_bf16(afr[s], bfr[1][s], acc1, 0, 0, 0);
    }

#pragma unroll
    for (int t = 0; t < 2; ++t) {
      int n = ncol0 + t * 16 + l15;
      float bo = t ? bo1 : bo0;
#pragma unroll
      for (int r = 0; r < 4; ++r) {
        int m = rowBase + rt * 16 + lhi * 4 + r;
        if (m < NND) {
          size_t off = (size_t)m * HD + n;
          float av = t ? acc1[r] : acc0[r];
          float kv = tanhf(av + bo);
          if (stage == 0) {
            ybf[off] = f2bf(bf2f(hbf[off]) + cy * kv);
            kacc[off] = f2bf(wk * kv);
            k8w[off] = f2fp8(kv);
          } else if (stage < 3) {
            ybf[off] = f2bf(bf2f(hbf[off]) + cy * kv);
            kacc[off] = f2bf(bf2f(kacc[off]) + wk * kv);
            k8w[off] = f2fp8(kv);
          } else {
            float hn = hfp[off] + bf2f(kacc[off]) + wk * kv;
            hfp[off] = hn;
            hbfout[off] = f2bf(hn);
          }
        }
      }
    }
  }
}

// ---------------- interference ----------------
__global__ __launch_bounds__(256) void k_interf(
    const float* __restrict__ h, const float* __restrict__ weff,
    const float* __restrict__ bint, const float* __restrict__ gint,
    const float* __restrict__ beint,
    const float* __restrict__ alphap, const float* __restrict__ betap,
    const float* __restrict__ phasep,
    float* __restrict__ h2out)
{
  __shared__ float As[64][16];
  __shared__ float Bs[16][128];
  int tid = threadIdx.x;
  int tx = tid & 31, ty = tid >> 5;
  int rowBase = blockIdx.x * 64;
  float acc[8][4];
#pragma unroll
  for (int i = 0; i < 8; ++i) { acc[i][0]=0.f; acc[i][1]=0.f; acc[i][2]=0.f; acc[i][3]=0.f; }

  for (int kc = 0; kc < 8; ++kc) {
    int k0 = kc * 16;
    {
      int r = tid >> 2, kq = (tid & 3) * 4;
      int row = rowBase + r; if (row >= NND) row = NND - 1;
      *(float4*)&As[r][kq] = *(const float4*)&h[(size_t)row * HD + k0 + kq];
    }
#pragma unroll
    for (int j = 0; j < 2; ++j) {
      int kk = (tid >> 5) + j * 8;
      int n = (tid & 31) * 4;
      *(float4*)&Bs[kk][n] = *(const float4*)&weff[(k0 + kk) * HD + n];
    }
    __syncthreads();
#pragma unroll
    for (int kq = 0; kq < 4; ++kq) {
      float4 b0 = *(float4*)&Bs[kq*4+0][tx*4];
      float4 b1 = *(float4*)&Bs[kq*4+1][tx*4];
      float4 b2 = *(float4*)&Bs[kq*4+2][tx*4];
      float4 b3 = *(float4*)&Bs[kq*4+3][tx*4];
#pragma unroll
      for (int i = 0; i < 8; ++i) {
        float4 a = *(float4*)&As[ty*8+i][kq*4];
        acc[i][0] = fmaf(a.x,b0.x,fmaf(a.y,b1.x,fmaf(a.z,b2.x,fmaf(a.w,b3.x,acc[i][0]))));
        acc[i][1] = fmaf(a.x,b0.y,fmaf(a.y,b1.y,fmaf(a.z,b2.y,fmaf(a.w,b3.y,acc[i][1]))));
        acc[i][2] = fmaf(a.x,b0.z,fmaf(a.y,b1.z,fmaf(a.z,b2.z,fmaf(a.w,b3.z,acc[i][2]))));
        acc[i][3] = fmaf(a.x,b0.w,fmaf(a.y,b1.w,fmaf(a.z,b2.w,fmaf(a.w,b3.w,acc[i][3]))));
      }
    }
    __syncthreads();
  }

  float al = alphap[0], bt = betap[0], ph = phasep[0];
  float n2 = al*al + bt*bt;
  float p0 = (al*al) / n2, p1 = (bt*bt) / n2;
  float interf = 2.0f * sqrtf(p0 * p1) * cosf(ph);
  float gate = (fabsf(interf) > 0.01f) ? interf : 0.0f;
  float cscale = (p0 > p1) ? 1.0f : cosf(ph);

  int c0 = tx * 4;
  float4 bi  = *(const float4*)&bint[c0];
  float4 gv  = *(const float4*)&gint[c0];
  float4 bev = *(const float4*)&beint[c0];
#pragma unroll
  for (int i = 0; i < 8; ++i) {
    int row = rowBase + ty*8 + i;
    float z0 = acc[i][0]+bi.x, z1 = acc[i][1]+bi.y, z2 = acc[i][2]+bi.z, z3 = acc[i][3]+bi.w;
    float rsum = z0+z1+z2+z3;
    float rsq  = z0*z0+z1*z1+z2*z2+z3*z3;
#pragma unroll
    for (int m = 1; m < 32; m <<= 1) { rsum += __shfl_xor(rsum, m, 32); rsq += __shfl_xor(rsq, m, 32); }
    float mean = rsum * (1.0f/128.0f);
    float var  = rsq * (1.0f/128.0f) - mean*mean;
    float rs = rsqrtf(var + 1e-5f);
    float t0 = tanhf((z0-mean)*rs*gv.x + bev.x);
    float t1 = tanhf((z1-mean)*rs*gv.y + bev.y);
    float t2 = tanhf((z2-mean)*rs*gv.z + bev.z);
    float t3 = tanhf((z3-mean)*rs*gv.w + bev.w);
    if (row < NND) {
      size_t off = (size_t)row * HD + c0;
      float4 hv = *(const float4*)&h[off];
      float4 o = make_float4((hv.x + gate*t0) * cscale,
                             (hv.y + gate*t1) * cscale,
                             (hv.z + gate*t2) * cscale,
                             (hv.w + gate*t3) * cscale);
      *(float4*)&h2out[off] = o;
    }
  }
}

// ---------------- output GEMM + pooled atomic accumulation ----------------
__global__ __launch_bounds__(256) void k_out(
    const float* __restrict__ h2, const float* __restrict__ Wout,
    const float* __restrict__ bout, const int* __restrict__ batch,
    float* __restrict__ pooled)
{
  __shared__ float As[64][16];
  __shared__ float Bs[16][128];
  int tid = threadIdx.x;
  int tx = tid & 31, ty = tid >> 5;
  int rowBase = blockIdx.x * 64;
  float acc[8][4];
#pragma unroll
  for (int i = 0; i < 8; ++i) { acc[i][0]=0.f; acc[i][1]=0.f; acc[i][2]=0.f; acc[i][3]=0.f; }

  for (int kc = 0; kc < 8; ++kc) {
    int k0 = kc * 16;
    {
      int r = tid >> 2, kq = (tid & 3) * 4;
      int row = rowBase + r; if (row >= NND) row = NND - 1;
      *(float4*)&As[r][kq] = *(const float4*)&h2[(size_t)row * HD + k0 + kq];
    }
#pragma unroll
    for (int j = 0; j < 2; ++j) {
      int kk = (tid >> 5) + j * 8;
      int n = (tid & 31) * 4;
      *(float4*)&Bs[kk][n] = *(const float4*)&Wout[(k0 + kk) * HD + n];
    }
    __syncthreads();
#pragma unroll
    for (int kq = 0; kq < 4; ++kq) {
      float4 b0 = *(float4*)&Bs[kq*4+0][tx*4];
      float4 b1 = *(float4*)&Bs[kq*4+1][tx*4];
      float4 b2 = *(float4*)&Bs[kq*4+2][tx*4];
      float4 b3 = *(float4*)&Bs[kq*4+3][tx*4];
#pragma unroll
      for (int i = 0; i < 8; ++i) {
        float4 a = *(float4*)&As[ty*8+i][kq*4];
        acc[i][0] = fmaf(a.x,b0.x,fmaf(a.y,b1.x,fmaf(a.z,b2.x,fmaf(a.w,b3.x,acc[i][0]))));
        acc[i][1] = fmaf(a.x,b0.y,fmaf(a.y,b1.y,fmaf(a.z,b2.y,fmaf(a.w,b3.y,acc[i][1]))));
        acc[i][2] = fmaf(a.x,b0.z,fmaf(a.y,b1.z,fmaf(a.z,b2.z,fmaf(a.w,b3.z,acc[i][2]))));
        acc[i][3] = fmaf(a.x,b0.w,fmaf(a.y,b1.w,fmaf(a.z,b2.w,fmaf(a.w,b3.w,acc[i][3]))));
      }
    }
    __syncthreads();
  }

  int c0 = tx * 4;
  float4 bo = *(const float4*)&bout[c0];
  int prevg = -1;
  float r0 = 0.f, r1 = 0.f, r2 = 0.f, r3 = 0.f;
#pragma unroll
  for (int i = 0; i < 8; ++i) {
    int row = rowBase + ty*8 + i;
    if (row >= NND) break;
    int g = batch[row];
    float v0 = acc[i][0] + bo.x;
    float v1 = acc[i][1] + bo.y;
    float v2 = acc[i][2] + bo.z;
    float v3 = acc[i][3] + bo.w;
    if (g != prevg) {
      if (prevg >= 0) {
        atomicAdd(&pooled[prevg*HD + c0 + 0], r0);
        atomicAdd(&pooled[prevg*HD + c0 + 1], r1);
        atomicAdd(&pooled[prevg*HD + c0 + 2], r2);
        atomicAdd(&pooled[prevg*HD + c0 + 3], r3);
      }
      prevg = g; r0 = v0; r1 = v1; r2 = v2; r3 = v3;
    } else {
      r0 += v0; r1 += v1; r2 += v2; r3 += v3;
    }
  }
  if (prevg >= 0) {
    atomicAdd(&pooled[prevg*HD + c0 + 0], r0);
    atomicAdd(&pooled[prevg*HD + c0 + 1], r1);
    atomicAdd(&pooled[prevg*HD + c0 + 2], r2);
    atomicAdd(&pooled[prevg*HD + c0 + 3], r3);
  }
}

__global__ void k_final(const float* __restrict__ pooled, const float* __restrict__ cnt,
                        float* __restrict__ out) {
  int i = blockIdx.x * 256 + threadIdx.x;
  if (i < NG * HD) out[i] = pooled[i] / fmaxf(cnt[i >> 7], 1.0f);
}

extern "C" void kernel_launch(void* const* d_in, const int* in_sizes, int n_in,
                              void* d_out, int out_size, void* d_ws, size_t ws_size,
                              hipStream_t stream) {
  (void)in_sizes; (void)n_in; (void)out_size; (void)ws_size;
  const float* x     = (const float*)d_in[0];
  const int*   ei    = (const int*)d_in[1];
  const int*   batch = (const int*)d_in[2];
  const float* alpha = (const float*)d_in[3];
  const float* beta  = (const float*)d_in[4];
  const float* phase = (const float*)d_in[5];
  const float* Win   = (const float*)d_in[6];
  const float* bin   = (const float*)d_in[7];
  const float* gin   = (const float*)d_in[8];
  const float* bein  = (const float*)d_in[9];
  const float* Walt  = (const float*)d_in[10];
  const float* balt  = (const float*)d_in[11];
  const float* galt  = (const float*)d_in[12];
  const float* bealt = (const float*)d_in[13];
  const float* Wself = (const float*)d_in[14];
  const float* Wmsg  = (const float*)d_in[15];
  const float* bode  = (const float*)d_in[16];
  const float* Wint  = (const float*)d_in[17];
  const float* bint  = (const float*)d_in[18];
  const float* gint  = (const float*)d_in[19];
  const float* beint = (const float*)d_in[20];
  const float* Wout  = (const float*)d_in[21];
  const float* bout  = (const float*)d_in[22];
  float* out = (float*)d_out;

  const int* esrc = ei;
  const int* edst = ei + NED;

  size_t NH = (size_t)NND * HD;   // 6,400,000
  float* h      = (float*)d_ws;
  float* h2     = h + NH;
  float* deginv = h2 + NH;
  float* weff   = deginv + NND;
  float* pooled = weff + HD * HD;
  float* cnt    = pooled + NG * HD;
  unsigned short* hbf  = (unsigned short*)(cnt + NG);
  unsigned short* ybf  = hbf + NH;
  unsigned short* usav = ybf + NH;
  unsigned short* kacc = usav + NH;
  unsigned short* Bt   = kacc + NH;          // 128*256
  unsigned short* BtIn = Bt + 128 * 256;     // 2*128*128
  unsigned char* k8a = (unsigned char*)(BtIn + 2 * 128 * 128);
  unsigned char* k8b = k8a + NH;
  int* degi   = (int*)(k8b + NH);
  int* rowptr = degi + NND;
  int* cursor = rowptr + (NND + 4);
  int* csrsrc = cursor + NND;

  hipMemsetAsync(degi, 0, NND * sizeof(int), stream);
  hipMemsetAsync(pooled, 0, NG * HD * sizeof(float), stream);

  k_hist   <<<(NED + 255) / 256, 256, 0, stream>>>(edst, degi);
  k_scan   <<<1, 1024, 0, stream>>>(degi, rowptr, cursor, deginv);
  k_scatter<<<(NED + 255) / 256, 256, 0, stream>>>(esrc, edst, cursor, csrsrc);
  k_cnt    <<<1, 64, 0, stream>>>(batch, cnt);
  k_weff   <<<(HD * HD + 255) / 256, 256, 0, stream>>>(Wint, weff);
  k_prepB  <<<128, 256, 0, stream>>>(Wself, Wmsg, Bt);
  k_prepIn <<<128, 256, 0, stream>>>(Win, Walt, BtIn);
  k_init2  <<<(NND + 63) / 64, 256, 0, stream>>>(x, BtIn, bin, gin, bein,
                                                 balt, galt, bealt,
                                                 alpha, beta, h, hbf);
  int nblk = (NND + MT - 1) / MT;
  for (int step = 0; step < 8; ++step) {
    for (int stage = 0; stage < 4; ++stage) {
      const unsigned short* ain = (stage == 0) ? hbf : ybf;
      const unsigned char* k8r = (stage == 2) ? k8b : k8a;
      unsigned char* k8w = (stage == 1) ? k8b : k8a;
      k_fused<<<nblk, 256, 0, stream>>>(ain, hbf, k8r, k8w, usav, kacc,
                                        rowptr, csrsrc, deginv, Bt, bode,
                                        h, ybf, hbf, stage);
    }
  }
  k_interf<<<(NND + 63) / 64, 256, 0, stream>>>(h, weff, bint, gint, beint,
                                                alpha, beta, phase, h2);
  k_out   <<<(NND + 63) / 64, 256, 0, stream>>>(h2, Wout, bout, batch, pooled);
  k_final <<<(NG * HD + 255) / 256, 256, 0, stream>>>(pooled, cnt, out);
}

// Round 7
// 2028.743 us; speedup vs baseline: 1.1496x; 1.1496x over previous
//
#include <hip/hip_runtime.h>
#include <math.h>

#define NND 50000
#define NED 800000
#define HD  128
#define NG  64
#define MT  64

typedef __attribute__((ext_vector_type(8))) short short8v;
typedef __attribute__((ext_vector_type(4))) float float4v;
typedef __attribute__((ext_vector_type(2))) float float2v;

__device__ __forceinline__ float gelu_t(float x) {
  const float c = 0.7978845608028654f;
  float t = tanhf(c * (x + 0.044715f * x * x * x));
  return 0.5f * x * (1.0f + t);
}

__device__ __forceinline__ unsigned short f2bf(float f) {
  unsigned int u = __float_as_uint(f);
  u += 0x7FFFu + ((u >> 16) & 1u);
  return (unsigned short)(u >> 16);
}
__device__ __forceinline__ float bf2f(unsigned short s) {
  return __uint_as_float(((unsigned int)s) << 16);
}
__device__ __forceinline__ float bflo(unsigned int u) { return __uint_as_float(u << 16); }
__device__ __forceinline__ float bfhi(unsigned int u) { return __uint_as_float(u & 0xFFFF0000u); }
__device__ __forceinline__ unsigned char f2fp8(float f) {
  return (unsigned char)(__builtin_amdgcn_cvt_pk_fp8_f32(f, f, 0, false) & 0xFF);
}

// ---------------- CSR build ----------------
__global__ void k_hist(const int* __restrict__ dst, int* __restrict__ degi) {
  int e = blockIdx.x * 256 + threadIdx.x;
  if (e < NED) atomicAdd(&degi[dst[e]], 1);
}

__global__ __launch_bounds__(1024) void k_scan(
    const int* __restrict__ degi, int* __restrict__ rowptr,
    int* __restrict__ cursor, float* __restrict__ deginv) {
  __shared__ int wsum[16];
  int tid = threadIdx.x;
  int lane = tid & 63;
  int wid = tid >> 6;
  int running = 0;
  for (int base = 0; base < NND; base += 1024) {
    int idx = base + tid;
    int v = (idx < NND) ? degi[idx] : 0;
    int s = v;
#pragma unroll
    for (int o = 1; o < 64; o <<= 1) {
      int t = __shfl_up(s, o, 64);
      if (lane >= o) s += t;
    }
    if (lane == 63) wsum[wid] = s;
    __syncthreads();
    if (wid == 0) {
      int ws = (lane < 16) ? wsum[lane] : 0;
#pragma unroll
      for (int o = 1; o < 16; o <<= 1) {
        int t = __shfl_up(ws, o, 64);
        if (lane >= o) ws += t;
      }
      if (lane < 16) wsum[lane] = ws;
    }
    __syncthreads();
    int woff = wid ? wsum[wid - 1] : 0;
    int excl = running + woff + s - v;
    if (idx < NND) {
      rowptr[idx] = excl;
      cursor[idx] = excl;
      deginv[idx] = 1.0f / (float)max(v, 1);
    }
    int tot = wsum[15];
    __syncthreads();
    running += tot;
  }
  if (tid == 0) rowptr[NND] = running;
}

__global__ void k_scatter(const int* __restrict__ src, const int* __restrict__ dst,
                          int* __restrict__ cursor, int* __restrict__ csrsrc) {
  int e = blockIdx.x * 256 + threadIdx.x;
  if (e < NED) {
    int d = dst[e];
    int pos = atomicAdd(&cursor[d], 1);
    csrsrc[pos] = src[e];
  }
}

__global__ void k_cnt(const int* __restrict__ batch, float* __restrict__ cnt) {
  int g = threadIdx.x;
  if (g >= NG) return;
  int lo, hi, ub_g, ub_gm1;
  lo = 0; hi = NND;
  while (lo < hi) { int mid = (lo + hi) >> 1; if (batch[mid] <= g) lo = mid + 1; else hi = mid; }
  ub_g = lo;
  if (g == 0) ub_gm1 = 0;
  else {
    lo = 0; hi = NND;
    int v = g - 1;
    while (lo < hi) { int mid = (lo + hi) >> 1; if (batch[mid] <= v) lo = mid + 1; else hi = mid; }
    ub_gm1 = lo;
  }
  cnt[g] = (float)(ub_g - ub_gm1);
}

__global__ void k_weff(const float* __restrict__ Wint, float* __restrict__ weff) {
  int i = blockIdx.x * 256 + threadIdx.x;
  if (i < HD * HD) weff[i] = Wint[i] + Wint[i + HD * HD];
}

__global__ void k_prepB(const float* __restrict__ Wself, const float* __restrict__ Wmsg,
                        unsigned short* __restrict__ Bt) {
  int i = blockIdx.x * 256 + threadIdx.x;
  if (i < 128 * 256) {
    int n = i >> 8, k = i & 255;
    float w = (k < HD) ? Wself[k * HD + n] : Wmsg[(k - HD) * HD + n];
    Bt[i] = f2bf(w);
  }
}

__global__ void k_prepIn(const float* __restrict__ Win, const float* __restrict__ Walt,
                         unsigned short* __restrict__ BtIn) {
  int i = blockIdx.x * 256 + threadIdx.x;
  if (i < 2 * 128 * 128) {
    int p = i >> 14; int rem = i & 16383; int n = rem >> 7; int k = rem & 127;
    const float* W = p ? Walt : Win;
    BtIn[i] = f2bf(W[k * 128 + n]);
  }
}

// ---------------- init (MFMA): writes hbf only ----------------
__global__ __launch_bounds__(256) void k_init2(
    const float* __restrict__ x, const unsigned short* __restrict__ BtIn,
    const float* __restrict__ bin, const float* __restrict__ gin, const float* __restrict__ bein,
    const float* __restrict__ balt, const float* __restrict__ galt, const float* __restrict__ bealt,
    const float* __restrict__ alphap, const float* __restrict__ betap,
    unsigned short* __restrict__ hbf)
{
  __shared__ float red[4][16][2];
  __shared__ unsigned short gtile[2][16][64];
  int tid = threadIdx.x;
  int wave = tid >> 6;
  int lane = tid & 63;
  int l15 = lane & 15;
  int lhi = lane >> 4;
  int path = wave >> 1;
  int colBase = (wave & 1) * 64;
  int rowBase = blockIdx.x * 64;

  const unsigned short* Bp = BtIn + path * 128 * 128;
  short8v bfr[4][4];
#pragma unroll
  for (int t = 0; t < 4; ++t) {
    int n = colBase + t * 16 + l15;
#pragma unroll
    for (int s = 0; s < 4; ++s)
      bfr[t][s] = *(const short8v*)&Bp[n * 128 + s * 32 + lhi * 8];
  }

  const float* bvp = path ? balt : bin;
  const float* gp  = path ? galt : gin;
  const float* bep = path ? bealt : bein;
  float bv[4], gw[4], bew[4];
#pragma unroll
  for (int t = 0; t < 4; ++t) {
    int col = colBase + t * 16 + l15;
    bv[t] = bvp[col]; gw[t] = gp[col]; bew[t] = bep[col];
  }

  float al = alphap[0], btv = betap[0];
  float nrm = sqrtf(al * al + btv * btv);
  float w0 = fabsf(al) / nrm, w1 = fabsf(btv) / nrm;

  for (int rt = 0; rt < 4; ++rt) {
    int arow = rowBase + rt * 16 + l15; if (arow >= NND) arow = NND - 1;
    short8v afr[4];
#pragma unroll
    for (int s = 0; s < 4; ++s) {
      float4 xa = *(const float4*)&x[(size_t)arow * HD + s * 32 + lhi * 8];
      float4 xb = *(const float4*)&x[(size_t)arow * HD + s * 32 + lhi * 8 + 4];
      short8v f;
      f[0] = (short)f2bf(xa.x); f[1] = (short)f2bf(xa.y);
      f[2] = (short)f2bf(xa.z); f[3] = (short)f2bf(xa.w);
      f[4] = (short)f2bf(xb.x); f[5] = (short)f2bf(xb.y);
      f[6] = (short)f2bf(xb.z); f[7] = (short)f2bf(xb.w);
      afr[s] = f;
    }

    float4v acc[4];
#pragma unroll
    for (int t = 0; t < 4; ++t) acc[t] = (float4v){0.f, 0.f, 0.f, 0.f};
#pragma unroll
    for (int s = 0; s < 4; ++s) {
#pragma unroll
      for (int t = 0; t < 4; ++t)
        acc[t] = __builtin_amdgcn_mfma_f32_16x16x32_bf16(afr[s], bfr[t][s], acc[t], 0, 0, 0);
    }

    float z[4][4];
    float psum[4], psq[4];
#pragma unroll
    for (int r = 0; r < 4; ++r) {
      float s1 = 0.f, s2 = 0.f;
#pragma unroll
      for (int t = 0; t < 4; ++t) {
        float zz = acc[t][r] + bv[t];
        z[r][t] = zz;
        s1 += zz; s2 += zz * zz;
      }
#pragma unroll
      for (int m = 1; m < 16; m <<= 1) {
        s1 += __shfl_xor(s1, m, 16);
        s2 += __shfl_xor(s2, m, 16);
      }
      psum[r] = s1; psq[r] = s2;
    }
    if (l15 == 0) {
#pragma unroll
      for (int r = 0; r < 4; ++r) {
        red[wave][lhi * 4 + r][0] = psum[r];
        red[wave][lhi * 4 + r][1] = psq[r];
      }
    }
    __syncthreads();

    int pw = wave ^ 1;
    float gval[4][4];
#pragma unroll
    for (int r = 0; r < 4; ++r) {
      int rowl = lhi * 4 + r;
      float S = psum[r] + red[pw][rowl][0];
      float Q = psq[r]  + red[pw][rowl][1];
      float mean = S * (1.0f / 128.0f);
      float var  = Q * (1.0f / 128.0f) - mean * mean;
      float rs = rsqrtf(var + 1e-5f);
#pragma unroll
      for (int t = 0; t < 4; ++t)
        gval[r][t] = gelu_t((z[r][t] - mean) * rs * gw[t] + bew[t]);
    }

    if (path == 1) {
#pragma unroll
      for (int r = 0; r < 4; ++r)
#pragma unroll
        for (int t = 0; t < 4; ++t)
          gtile[wave & 1][lhi * 4 + r][t * 16 + l15] = f2bf(gval[r][t]);
    }
    __syncthreads();

    if (path == 0) {
#pragma unroll
      for (int r = 0; r < 4; ++r) {
        int m = rowBase + rt * 16 + lhi * 4 + r;
        if (m < NND) {
#pragma unroll
          for (int t = 0; t < 4; ++t) {
            float g1 = bf2f(gtile[wave & 1][lhi * 4 + r][t * 16 + l15]);
            float hv = w0 * gval[r][t] + w1 * g1;
            hbf[(size_t)m * HD + colBase + t * 16 + l15] = f2bf(hv);
          }
        }
      }
    }
    __syncthreads();
  }
}

// ---------------- fused stage ----------------
// mode 0: step0-stage0: u = meanagg(hbf) [bf16]; usav = u
// mode 1: stage0:       u = usav + meanagg(dh8)/8; usav = u
// mode 2,3,4: stage1-3: u = usav + cu*meanagg(k8r)
// epilogue: kv = tanh(.)
//  mode<=1: ybf = bf(h + dt/2 kv); kacc = bf(dt/6 kv); k8w = fp8(kv)
//  mode 2:  ybf = bf(h + dt/2 kv); kacc += dt/3 kv;    k8w = fp8(kv)
//  mode 3:  ybf = bf(h + dt  kv);  kacc += dt/3 kv;    k8w = fp8(kv)
//  mode 4:  dh = kacc + dt/6 kv; h += dh (bf16 in place); dh8 = fp8(8*dh)
__global__ __launch_bounds__(256) void k_fused(
    const unsigned short* __restrict__ ain,
    unsigned short* __restrict__ hbf,
    const unsigned char* __restrict__ gsrc8,
    unsigned char* __restrict__ k8w,
    unsigned char* __restrict__ dh8,
    unsigned short* __restrict__ usav,
    unsigned short* __restrict__ kacc,
    const int* __restrict__ rowptr, const int* __restrict__ csrsrc,
    const float* __restrict__ deginv,
    const unsigned short* __restrict__ Bt, const float* __restrict__ bode,
    unsigned short* __restrict__ ybf, int mode)
{
  __shared__ unsigned char u_lds[MT * 256];   // MT rows x 128 bf16, XOR-swizzled
  int tid = threadIdx.x;
  int wave = tid >> 6;
  int lane = tid & 63;
  int l15 = lane & 15;
  int lhi = lane >> 4;
  int rowBase = blockIdx.x * MT;
  int ncol0 = wave * 32;

  const float DT = 0.125f;

  if (mode == 0) {
    // ---- bf16 gather of hbf rows: 16-lane groups ----
    int l16 = tid & 15;
    int grp = tid >> 4;
#pragma unroll
    for (int g = 0; g < MT / 16; ++g) {
      int nloc = g * 16 + grp;
      int node = rowBase + nloc;
      if (node < NND) {
        int e0 = rowptr[node], e1 = rowptr[node + 1];
        float a0=0,a1=0,a2=0,a3=0,a4=0,a5=0,a6=0,a7=0;
        for (int eb = e0; eb < e1; eb += 16) {
          int rem = e1 - eb;
          int idx0 = eb + ((l16 < rem) ? l16 : rem - 1);
          int my = csrsrc[idx0];
          int n16 = (rem < 16) ? rem : 16;
#pragma unroll
          for (int j = 0; j < 16; ++j) {
            if (j < n16) {
              int s = __shfl(my, j, 16);
              uint4 v = *(const uint4*)&hbf[(size_t)s * HD + l16 * 8];
              a0 += bflo(v.x); a1 += bfhi(v.x); a2 += bflo(v.y); a3 += bfhi(v.y);
              a4 += bflo(v.z); a5 += bfhi(v.z); a6 += bflo(v.w); a7 += bfhi(v.w);
            }
          }
        }
        float di = deginv[node];
        uint4 o;
        o.x = (unsigned int)f2bf(a0*di) | ((unsigned int)f2bf(a1*di) << 16);
        o.y = (unsigned int)f2bf(a2*di) | ((unsigned int)f2bf(a3*di) << 16);
        o.z = (unsigned int)f2bf(a4*di) | ((unsigned int)f2bf(a5*di) << 16);
        o.w = (unsigned int)f2bf(a6*di) | ((unsigned int)f2bf(a7*di) << 16);
        unsigned int boff = (unsigned int)nloc * 256u +
            (((unsigned int)l16 * 16u) ^ (((unsigned int)nloc & 7u) << 4));
        *(uint4*)&u_lds[boff] = o;
        *(uint4*)&usav[(size_t)node * HD + l16 * 8] = o;
      }
    }
  } else {
    // ---- fp8 gather: 8-lane groups, 128B rows, 16-deep MLP ----
    float dscale = (mode == 1) ? 0.125f : ((mode == 4) ? DT : 0.5f * DT);
    int l8 = tid & 7;
    int grp = tid >> 3;   // 0..31
#pragma unroll
    for (int g = 0; g < MT / 32; ++g) {
      int nloc = g * 32 + grp;
      int node = rowBase + nloc;
      if (node < NND) {
        int e0 = rowptr[node], e1 = rowptr[node + 1];
        float a[16];
#pragma unroll
        for (int q = 0; q < 16; ++q) a[q] = 0.f;
        for (int eb = e0; eb < e1; eb += 16) {
          int rem = e1 - eb;
          int my0 = csrsrc[eb + ((l8 < rem) ? l8 : rem - 1)];
          int my1 = (rem > 8) ? csrsrc[eb + 8 + ((l8 < rem - 8) ? l8 : rem - 9)] : 0;
          int n16 = (rem < 16) ? rem : 16;
          uint4 v[16];
#pragma unroll
          for (int j = 0; j < 16; ++j) {
            if (j < n16) {
              int s = (j < 8) ? __shfl(my0, j, 8) : __shfl(my1, j - 8, 8);
              v[j] = *(const uint4*)&gsrc8[(size_t)s * HD + l8 * 16];
            }
          }
#pragma unroll
          for (int j = 0; j < 16; ++j) {
            if (j < n16) {
              float2v f0 = __builtin_amdgcn_cvt_pk_f32_fp8(v[j].x, false);
              float2v f1 = __builtin_amdgcn_cvt_pk_f32_fp8(v[j].x, true);
              float2v f2 = __builtin_amdgcn_cvt_pk_f32_fp8(v[j].y, false);
              float2v f3 = __builtin_amdgcn_cvt_pk_f32_fp8(v[j].y, true);
              float2v f4 = __builtin_amdgcn_cvt_pk_f32_fp8(v[j].z, false);
              float2v f5 = __builtin_amdgcn_cvt_pk_f32_fp8(v[j].z, true);
              float2v f6 = __builtin_amdgcn_cvt_pk_f32_fp8(v[j].w, false);
              float2v f7 = __builtin_amdgcn_cvt_pk_f32_fp8(v[j].w, true);
              a[0]+=f0[0]; a[1]+=f0[1]; a[2]+=f1[0]; a[3]+=f1[1];
              a[4]+=f2[0]; a[5]+=f2[1]; a[6]+=f3[0]; a[7]+=f3[1];
              a[8]+=f4[0]; a[9]+=f4[1]; a[10]+=f5[0]; a[11]+=f5[1];
              a[12]+=f6[0]; a[13]+=f6[1]; a[14]+=f7[0]; a[15]+=f7[1];
            }
          }
        }
        float di = deginv[node] * dscale;
        uint4 us0 = *(const uint4*)&usav[(size_t)node * HD + l8 * 16];
        uint4 us1 = *(const uint4*)&usav[(size_t)node * HD + l8 * 16 + 8];
        float u0  = bflo(us0.x) + a[0]*di,  u1  = bfhi(us0.x) + a[1]*di;
        float u2  = bflo(us0.y) + a[2]*di,  u3  = bfhi(us0.y) + a[3]*di;
        float u4  = bflo(us0.z) + a[4]*di,  u5  = bfhi(us0.z) + a[5]*di;
        float u6  = bflo(us0.w) + a[6]*di,  u7  = bfhi(us0.w) + a[7]*di;
        float u8  = bflo(us1.x) + a[8]*di,  u9  = bfhi(us1.x) + a[9]*di;
        float u10 = bflo(us1.y) + a[10]*di, u11 = bfhi(us1.y) + a[11]*di;
        float u12 = bflo(us1.z) + a[12]*di, u13 = bfhi(us1.z) + a[13]*di;
        float u14 = bflo(us1.w) + a[14]*di, u15 = bfhi(us1.w) + a[15]*di;
        uint4 o0, o1;
        o0.x = (unsigned int)f2bf(u0)  | ((unsigned int)f2bf(u1)  << 16);
        o0.y = (unsigned int)f2bf(u2)  | ((unsigned int)f2bf(u3)  << 16);
        o0.z = (unsigned int)f2bf(u4)  | ((unsigned int)f2bf(u5)  << 16);
        o0.w = (unsigned int)f2bf(u6)  | ((unsigned int)f2bf(u7)  << 16);
        o1.x = (unsigned int)f2bf(u8)  | ((unsigned int)f2bf(u9)  << 16);
        o1.y = (unsigned int)f2bf(u10) | ((unsigned int)f2bf(u11) << 16);
        o1.z = (unsigned int)f2bf(u12) | ((unsigned int)f2bf(u13) << 16);
        o1.w = (unsigned int)f2bf(u14) | ((unsigned int)f2bf(u15) << 16);
        unsigned int base = (unsigned int)nloc * 256u;
        unsigned int sw = ((unsigned int)nloc & 7u) << 4;
        *(uint4*)&u_lds[base + (((unsigned int)l8 * 32u) ^ sw)] = o0;
        *(uint4*)&u_lds[base + (((unsigned int)l8 * 32u + 16u) ^ sw)] = o1;
        if (mode == 1) {
          *(uint4*)&usav[(size_t)node * HD + l8 * 16] = o0;
          *(uint4*)&usav[(size_t)node * HD + l8 * 16 + 8] = o1;
        }
      }
    }
  }

  // ---- B fragments ----
  short8v bfr[2][8];
#pragma unroll
  for (int t = 0; t < 2; ++t) {
    int n = ncol0 + t * 16 + l15;
#pragma unroll
    for (int s = 0; s < 8; ++s) {
      bfr[t][s] = *(const short8v*)&Bt[n * 256 + s * 32 + lhi * 8];
    }
  }
  float bo0 = bode[ncol0 + l15];
  float bo1 = bode[ncol0 + 16 + l15];

  __syncthreads();

  const float wk = (mode <= 1 || mode == 4) ? DT / 6.0f : DT / 3.0f;
  const float cy = (mode <= 2) ? 0.5f * DT : DT;

  // ---- MFMA + epilogue ----
#pragma unroll
  for (int rt = 0; rt < MT / 16; ++rt) {
    int rloc = rt * 16 + l15;
    int mload = rowBase + rloc;
    if (mload >= NND) mload = NND - 1;
    short8v afr[8];
#pragma unroll
    for (int s = 0; s < 4; ++s)
      afr[s] = *(const short8v*)&ain[(size_t)mload * HD + s * 32 + lhi * 8];
#pragma unroll
    for (int s = 0; s < 4; ++s) {
      unsigned int boff = (unsigned int)rloc * 256u +
        ((((unsigned int)s * 64u) + ((unsigned int)lhi * 16u)) ^ (((unsigned int)rloc & 7u) << 4));
      afr[4 + s] = *(const short8v*)&u_lds[boff];
    }

    float4v acc0 = {0.f, 0.f, 0.f, 0.f};
    float4v acc1 = {0.f, 0.f, 0.f, 0.f};
#pragma unroll
    for (int s = 0; s < 8; ++s) {
      acc0 = __builtin_amdgcn_mfma_f32_16x16x32_bf16(afr[s], bfr[0][s], acc0, 0, 0, 0);
      acc1 = __builtin_amdgcn_mfma_f32_16x16x32_bf16(afr[s], bfr[1][s], acc1, 0, 0, 0);
    }

#pragma unroll
    for (int t = 0; t < 2; ++t) {
      int n = ncol0 + t * 16 + l15;
      float bo = t ? bo1 : bo0;
#pragma unroll
      for (int r = 0; r < 4; ++r) {
        int m = rowBase + rt * 16 + lhi * 4 + r;
        if (m < NND) {
          size_t off = (size_t)m * HD + n;
          float av = t ? acc1[r] : acc0[r];
          float kv = tanhf(av + bo);
          if (mode <= 1) {
            ybf[off] = f2bf(bf2f(hbf[off]) + cy * kv);
            kacc[off] = f2bf(wk * kv);
            k8w[off] = f2fp8(kv);
          } else if (mode <= 3) {
            ybf[off] = f2bf(bf2f(hbf[off]) + cy * kv);
            kacc[off] = f2bf(bf2f(kacc[off]) + wk * kv);
            k8w[off] = f2fp8(kv);
          } else {
            float dh = bf2f(kacc[off]) + wk * kv;
            float hn = bf2f(hbf[off]) + dh;
            hbf[off] = f2bf(hn);
            dh8[off] = f2fp8(8.0f * dh);
          }
        }
      }
    }
  }
}

// ---------------- interference (bf16 h input) ----------------
__global__ __launch_bounds__(256) void k_interf(
    const unsigned short* __restrict__ hbf, const float* __restrict__ weff,
    const float* __restrict__ bint, const float* __restrict__ gint,
    const float* __restrict__ beint,
    const float* __restrict__ alphap, const float* __restrict__ betap,
    const float* __restrict__ phasep,
    float* __restrict__ h2out)
{
  __shared__ float As[64][16];
  __shared__ float Bs[16][128];
  int tid = threadIdx.x;
  int tx = tid & 31, ty = tid >> 5;
  int rowBase = blockIdx.x * 64;
  float acc[8][4];
#pragma unroll
  for (int i = 0; i < 8; ++i) { acc[i][0]=0.f; acc[i][1]=0.f; acc[i][2]=0.f; acc[i][3]=0.f; }

  for (int kc = 0; kc < 8; ++kc) {
    int k0 = kc * 16;
    {
      int r = tid >> 2, kq = (tid & 3) * 4;
      int row = rowBase + r; if (row >= NND) row = NND - 1;
      uint2 v = *(const uint2*)&hbf[(size_t)row * HD + k0 + kq];
      As[r][kq+0] = bflo(v.x); As[r][kq+1] = bfhi(v.x);
      As[r][kq+2] = bflo(v.y); As[r][kq+3] = bfhi(v.y);
    }
#pragma unroll
    for (int j = 0; j < 2; ++j) {
      int kk = (tid >> 5) + j * 8;
      int n = (tid & 31) * 4;
      *(float4*)&Bs[kk][n] = *(const float4*)&weff[(k0 + kk) * HD + n];
    }
    __syncthreads();
#pragma unroll
    for (int kq = 0; kq < 4; ++kq) {
      float4 b0 = *(float4*)&Bs[kq*4+0][tx*4];
      float4 b1 = *(float4*)&Bs[kq*4+1][tx*4];
      float4 b2 = *(float4*)&Bs[kq*4+2][tx*4];
      float4 b3 = *(float4*)&Bs[kq*4+3][tx*4];
#pragma unroll
      for (int i = 0; i < 8; ++i) {
        float4 a = *(float4*)&As[ty*8+i][kq*4];
        acc[i][0] = fmaf(a.x,b0.x,fmaf(a.y,b1.x,fmaf(a.z,b2.x,fmaf(a.w,b3.x,acc[i][0]))));
        acc[i][1] = fmaf(a.x,b0.y,fmaf(a.y,b1.y,fmaf(a.z,b2.y,fmaf(a.w,b3.y,acc[i][1]))));
        acc[i][2] = fmaf(a.x,b0.z,fmaf(a.y,b1.z,fmaf(a.z,b2.z,fmaf(a.w,b3.z,acc[i][2]))));
        acc[i][3] = fmaf(a.x,b0.w,fmaf(a.y,b1.w,fmaf(a.z,b2.w,fmaf(a.w,b3.w,acc[i][3]))));
      }
    }
    __syncthreads();
  }

  float al = alphap[0], bt = betap[0], ph = phasep[0];
  float n2 = al*al + bt*bt;
  float p0 = (al*al) / n2, p1 = (bt*bt) / n2;
  float interf = 2.0f * sqrtf(p0 * p1) * cosf(ph);
  float gate = (fabsf(interf) > 0.01f) ? interf : 0.0f;
  float cscale = (p0 > p1) ? 1.0f : cosf(ph);

  int c0 = tx * 4;
  float4 bi  = *(const float4*)&bint[c0];
  float4 gv  = *(const float4*)&gint[c0];
  float4 bev = *(const float4*)&beint[c0];
#pragma unroll
  for (int i = 0; i < 8; ++i) {
    int row = rowBase + ty*8 + i;
    float z0 = acc[i][0]+bi.x, z1 = acc[i][1]+bi.y, z2 = acc[i][2]+bi.z, z3 = acc[i][3]+bi.w;
    float rsum = z0+z1+z2+z3;
    float rsq  = z0*z0+z1*z1+z2*z2+z3*z3;
#pragma unroll
    for (int m = 1; m < 32; m <<= 1) { rsum += __shfl_xor(rsum, m, 32); rsq += __shfl_xor(rsq, m, 32); }
    float mean = rsum * (1.0f/128.0f);
    float var  = rsq * (1.0f/128.0f) - mean*mean;
    float rs = rsqrtf(var + 1e-5f);
    float t0 = tanhf((z0-mean)*rs*gv.x + bev.x);
    float t1 = tanhf((z1-mean)*rs*gv.y + bev.y);
    float t2 = tanhf((z2-mean)*rs*gv.z + bev.z);
    float t3 = tanhf((z3-mean)*rs*gv.w + bev.w);
    if (row < NND) {
      size_t off = (size_t)row * HD + c0;
      uint2 hv = *(const uint2*)&hbf[off];
      float h0 = bflo(hv.x), h1 = bfhi(hv.x), h2 = bflo(hv.y), h3 = bfhi(hv.y);
      float4 o = make_float4((h0 + gate*t0) * cscale,
                             (h1 + gate*t1) * cscale,
                             (h2 + gate*t2) * cscale,
                             (h3 + gate*t3) * cscale);
      *(float4*)&h2out[off] = o;
    }
  }
}

// ---------------- output GEMM + pooled atomic accumulation ----------------
__global__ __launch_bounds__(256) void k_out(
    const float* __restrict__ h2, const float* __restrict__ Wout,
    const float* __restrict__ bout, const int* __restrict__ batch,
    float* __restrict__ pooled)
{
  __shared__ float As[64][16];
  __shared__ float Bs[16][128];
  int tid = threadIdx.x;
  int tx = tid & 31, ty = tid >> 5;
  int rowBase = blockIdx.x * 64;
  float acc[8][4];
#pragma unroll
  for (int i = 0; i < 8; ++i) { acc[i][0]=0.f; acc[i][1]=0.f; acc[i][2]=0.f; acc[i][3]=0.f; }

  for (int kc = 0; kc < 8; ++kc) {
    int k0 = kc * 16;
    {
      int r = tid >> 2, kq = (tid & 3) * 4;
      int row = rowBase + r; if (row >= NND) row = NND - 1;
      *(float4*)&As[r][kq] = *(const float4*)&h2[(size_t)row * HD + k0 + kq];
    }
#pragma unroll
    for (int j = 0; j < 2; ++j) {
      int kk = (tid >> 5) + j * 8;
      int n = (tid & 31) * 4;
      *(float4*)&Bs[kk][n] = *(const float4*)&Wout[(k0 + kk) * HD + n];
    }
    __syncthreads();
#pragma unroll
    for (int kq = 0; kq < 4; ++kq) {
      float4 b0 = *(float4*)&Bs[kq*4+0][tx*4];
      float4 b1 = *(float4*)&Bs[kq*4+1][tx*4];
      float4 b2 = *(float4*)&Bs[kq*4+2][tx*4];
      float4 b3 = *(float4*)&Bs[kq*4+3][tx*4];
#pragma unroll
      for (int i = 0; i < 8; ++i) {
        float4 a = *(float4*)&As[ty*8+i][kq*4];
        acc[i][0] = fmaf(a.x,b0.x,fmaf(a.y,b1.x,fmaf(a.z,b2.x,fmaf(a.w,b3.x,acc[i][0]))));
        acc[i][1] = fmaf(a.x,b0.y,fmaf(a.y,b1.y,fmaf(a.z,b2.y,fmaf(a.w,b3.y,acc[i][1]))));
        acc[i][2] = fmaf(a.x,b0.z,fmaf(a.y,b1.z,fmaf(a.z,b2.z,fmaf(a.w,b3.z,acc[i][2]))));
        acc[i][3] = fmaf(a.x,b0.w,fmaf(a.y,b1.w,fmaf(a.z,b2.w,fmaf(a.w,b3.w,acc[i][3]))));
      }
    }
    __syncthreads();
  }

  int c0 = tx * 4;
  float4 bo = *(const float4*)&bout[c0];
  int prevg = -1;
  float r0 = 0.f, r1 = 0.f, r2 = 0.f, r3 = 0.f;
#pragma unroll
  for (int i = 0; i < 8; ++i) {
    int row = rowBase + ty*8 + i;
    if (row >= NND) break;
    int g = batch[row];
    float v0 = acc[i][0] + bo.x;
    float v1 = acc[i][1] + bo.y;
    float v2 = acc[i][2] + bo.z;
    float v3 = acc[i][3] + bo.w;
    if (g != prevg) {
      if (prevg >= 0) {
        atomicAdd(&pooled[prevg*HD + c0 + 0], r0);
        atomicAdd(&pooled[prevg*HD + c0 + 1], r1);
        atomicAdd(&pooled[prevg*HD + c0 + 2], r2);
        atomicAdd(&pooled[prevg*HD + c0 + 3], r3);
      }
      prevg = g; r0 = v0; r1 = v1; r2 = v2; r3 = v3;
    } else {
      r0 += v0; r1 += v1; r2 += v2; r3 += v3;
    }
  }
  if (prevg >= 0) {
    atomicAdd(&pooled[prevg*HD + c0 + 0], r0);
    atomicAdd(&pooled[prevg*HD + c0 + 1], r1);
    atomicAdd(&pooled[prevg*HD + c0 + 2], r2);
    atomicAdd(&pooled[prevg*HD + c0 + 3], r3);
  }
}

__global__ void k_final(const float* __restrict__ pooled, const float* __restrict__ cnt,
                        float* __restrict__ out) {
  int i = blockIdx.x * 256 + threadIdx.x;
  if (i < NG * HD) out[i] = pooled[i] / fmaxf(cnt[i >> 7], 1.0f);
}

extern "C" void kernel_launch(void* const* d_in, const int* in_sizes, int n_in,
                              void* d_out, int out_size, void* d_ws, size_t ws_size,
                              hipStream_t stream) {
  (void)in_sizes; (void)n_in; (void)out_size; (void)ws_size;
  const float* x     = (const float*)d_in[0];
  const int*   ei    = (const int*)d_in[1];
  const int*   batch = (const int*)d_in[2];
  const float* alpha = (const float*)d_in[3];
  const float* beta  = (const float*)d_in[4];
  const float* phase = (const float*)d_in[5];
  const float* Win   = (const float*)d_in[6];
  const float* bin   = (const float*)d_in[7];
  const float* gin   = (const float*)d_in[8];
  const float* bein  = (const float*)d_in[9];
  const float* Walt  = (const float*)d_in[10];
  const float* balt  = (const float*)d_in[11];
  const float* galt  = (const float*)d_in[12];
  const float* bealt = (const float*)d_in[13];
  const float* Wself = (const float*)d_in[14];
  const float* Wmsg  = (const float*)d_in[15];
  const float* bode  = (const float*)d_in[16];
  const float* Wint  = (const float*)d_in[17];
  const float* bint  = (const float*)d_in[18];
  const float* gint  = (const float*)d_in[19];
  const float* beint = (const float*)d_in[20];
  const float* Wout  = (const float*)d_in[21];
  const float* bout  = (const float*)d_in[22];
  float* out = (float*)d_out;

  const int* esrc = ei;
  const int* edst = ei + NED;

  size_t NH = (size_t)NND * HD;   // 6,400,000
  float* h2     = (float*)d_ws;
  float* deginv = h2 + NH;
  float* weff   = deginv + NND;
  float* pooled = weff + HD * HD;
  float* cnt    = pooled + NG * HD;
  unsigned short* hbf  = (unsigned short*)(cnt + NG);
  unsigned short* ybf  = hbf + NH;
  unsigned short* usav = ybf + NH;
  unsigned short* kacc = usav + NH;
  unsigned short* Bt   = kacc + NH;          // 128*256
  unsigned short* BtIn = Bt + 128 * 256;     // 2*128*128
  unsigned char* k8a = (unsigned char*)(BtIn + 2 * 128 * 128);
  unsigned char* k8b = k8a + NH;
  unsigned char* dh8 = k8b + NH;
  int* degi   = (int*)(dh8 + NH);
  int* rowptr = degi + NND;
  int* cursor = rowptr + (NND + 4);
  int* csrsrc = cursor + NND;

  hipMemsetAsync(degi, 0, NND * sizeof(int), stream);
  hipMemsetAsync(pooled, 0, NG * HD * sizeof(float), stream);

  k_hist   <<<(NED + 255) / 256, 256, 0, stream>>>(edst, degi);
  k_scan   <<<1, 1024, 0, stream>>>(degi, rowptr, cursor, deginv);
  k_scatter<<<(NED + 255) / 256, 256, 0, stream>>>(esrc, edst, cursor, csrsrc);
  k_cnt    <<<1, 64, 0, stream>>>(batch, cnt);
  k_weff   <<<(HD * HD + 255) / 256, 256, 0, stream>>>(Wint, weff);
  k_prepB  <<<128, 256, 0, stream>>>(Wself, Wmsg, Bt);
  k_prepIn <<<128, 256, 0, stream>>>(Win, Walt, BtIn);
  k_init2  <<<(NND + 63) / 64, 256, 0, stream>>>(x, BtIn, bin, gin, bein,
                                                 balt, galt, bealt,
                                                 alpha, beta, hbf);
  int nblk = (NND + MT - 1) / MT;
  for (int step = 0; step < 8; ++step) {
    // stage 0: gather dh8 (or full hbf at step 0), write k0 -> k8a
    k_fused<<<nblk, 256, 0, stream>>>(hbf, hbf, dh8, k8a, dh8, usav, kacc,
                                      rowptr, csrsrc, deginv, Bt, bode,
                                      ybf, (step == 0) ? 0 : 1);
    // stage 1: gather k8a (k0), write k1 -> k8b
    k_fused<<<nblk, 256, 0, stream>>>(ybf, hbf, k8a, k8b, dh8, usav, kacc,
                                      rowptr, csrsrc, deginv, Bt, bode,
                                      ybf, 2);
    // stage 2: gather k8b (k1), write k2 -> k8a
    k_fused<<<nblk, 256, 0, stream>>>(ybf, hbf, k8b, k8a, dh8, usav, kacc,
                                      rowptr, csrsrc, deginv, Bt, bode,
                                      ybf, 3);
    // stage 3: gather k8a (k2), update hbf in place, write dh8
    k_fused<<<nblk, 256, 0, stream>>>(ybf, hbf, k8a, k8b, dh8, usav, kacc,
                                      rowptr, csrsrc, deginv, Bt, bode,
                                      ybf, 4);
  }
  k_interf<<<(NND + 63) / 64, 256, 0, stream>>>(hbf, weff, bint, gint, beint,
                                                alpha, beta, phase, h2);
  k_out   <<<(NND + 63) / 64, 256, 0, stream>>>(h2, Wout, bout, batch, pooled);
  k_final <<<(NG * HD + 255) / 256, 256, 0, stream>>>(pooled, cnt, out);
}